// Round 5
// baseline (88.433 us; speedup 1.0000x reference)
//
#include <hip/hip_runtime.h>

#define Bn  4
#define Cn  64
#define Hn  96
#define Wn  96
#define Con 64
#define Kk  9
#define HW  (Hn*Wn)     // 9216
#define PIX 16
#define CK  (Cn*Kk)     // 576
#define NTILE (HW/PIX)  // 576

typedef __attribute__((ext_vector_type(8))) short bf16x8;
typedef __attribute__((ext_vector_type(4))) float f32x4;

static __device__ __forceinline__ float bf2f(ushort u) {
    return __uint_as_float(((unsigned int)u) << 16);
}
static __device__ __forceinline__ ushort f2bf(float f) {
    unsigned int u = __float_as_uint(f);
    u += 0x7FFFu + ((u >> 16) & 1u);   // RNE
    return (ushort)(u >> 16);
}

// ---------------- prep (merged): blocks 0..575 transpose NCHW->NHWC bf16,
//                  blocks 576..719 reorder weight f32 [o][c*9+k] -> bf16 [o][k*64+c]
__global__ __launch_bounds__(256) void dcnv2_prep(
    const float* __restrict__ in, const float* __restrict__ w,
    ushort* __restrict__ nhwc, ushort* __restrict__ wb)
{
    const int t = threadIdx.x;
    if (blockIdx.x < 576) {
        __shared__ ushort tile[64][66];
        const int bid = blockIdx.x;
        const int b  = bid / 144;
        const int s0 = (bid % 144) * 64;
        const float* ib = in + (size_t)b * Cn * HW;
        #pragma unroll
        for (int i = 0; i < 16; ++i) {
            const int c = i * 4 + (t >> 6);
            tile[t & 63][c] = f2bf(ib[(size_t)c * HW + s0 + (t & 63)]);
        }
        __syncthreads();
        ushort* ob = nhwc + ((size_t)b * HW + s0) * 64;
        #pragma unroll
        for (int i = 0; i < 16; ++i) {
            const int s = i * 4 + (t >> 6);
            ob[s * 64 + (t & 63)] = tile[s][t & 63];
        }
    } else {
        const int e = (blockIdx.x - 576) * 256 + t;
        if (e < Con * CK) {
            const int o  = e / CK;
            const int ck = e - o * CK;     // k*64 + c
            const int k  = ck >> 6;
            const int c  = ck & 63;
            wb[e] = f2bf(w[(size_t)o * CK + c * Kk + k]);
        }
    }
}

// ---------------- sample: barrier-free, LDS-free gather -> cols[P][576] bf16 ----------------
__global__ __launch_bounds__(256) void dcnv2_sample(
    const ushort* __restrict__ nhwc,   // [B][HW][64] bf16
    const float*  __restrict__ offset,
    const float*  __restrict__ mask,
    ushort* __restrict__ cols)         // [B*HW][576], row = blk*16+p, col = k*64+c
{
    const int t    = threadIdx.x;
    const int orig = blockIdx.x;
    const int blk  = (orig & 7) * 288 + (orig >> 3);   // XCD-bijective (2304 = 8*288)
    const int b    = blk / NTILE;
    const int tile = blk % NTILE;
    const int pix0 = tile * PIX;
    const int ho   = pix0 / Wn;
    const int p1   = t >> 4;           // pixel 0..15
    const int c4   = t & 15;           // channel quad
    const int wo   = (pix0 % Wn) + p1;
    const int sp   = ho * Wn + wo;

    const ushort* __restrict__ nb = nhwc + (size_t)b * HW * 64;
    const float*  __restrict__ ob = offset + (size_t)b * 2 * Kk * HW + sp;
    const float*  __restrict__ mb = mask   + (size_t)b * Kk * HW + sp;
    ushort* __restrict__ cp = cols + ((size_t)blk * PIX + p1) * CK + 4 * c4;

    #pragma unroll
    for (int k = 0; k < Kk; ++k) {
        const float dy = ob[(size_t)(2 * k) * HW];
        const float dx = ob[(size_t)(2 * k + 1) * HW];
        const float m  = mb[(size_t)k * HW];
        const float py = dy + (float)(k / 3) + (float)(ho - 1);
        const float px = dx + (float)(k % 3) + (float)(wo - 1);
        const float fy = floorf(py), fx = floorf(px);
        const int iy0 = (int)fy, ix0 = (int)fx;
        const int iy1 = iy0 + 1, ix1 = ix0 + 1;
        const float wy = py - fy, wx = px - fx;
        const float vy0 = (iy0 >= 0 && iy0 < Hn) ? 1.f : 0.f;
        const float vy1 = (iy1 >= 0 && iy1 < Hn) ? 1.f : 0.f;
        const float vx0 = (ix0 >= 0 && ix0 < Wn) ? 1.f : 0.f;
        const float vx1 = (ix1 >= 0 && ix1 < Wn) ? 1.f : 0.f;
        const int cy0 = min(max(iy0, 0), Hn - 1), cy1 = min(max(iy1, 0), Hn - 1);
        const int cx0 = min(max(ix0, 0), Wn - 1), cx1 = min(max(ix1, 0), Wn - 1);
        const float w00 = m * (1.f - wy) * (1.f - wx) * vy0 * vx0;
        const float w01 = m * (1.f - wy) * wx         * vy0 * vx1;
        const float w10 = m * wy         * (1.f - wx) * vy1 * vx0;
        const float w11 = m * wy         * wx         * vy1 * vx1;
        const ushort4 r00 = *(const ushort4*)(nb + (cy0 * Wn + cx0) * 64 + 4 * c4);
        const ushort4 r01 = *(const ushort4*)(nb + (cy0 * Wn + cx1) * 64 + 4 * c4);
        const ushort4 r10 = *(const ushort4*)(nb + (cy1 * Wn + cx0) * 64 + 4 * c4);
        const ushort4 r11 = *(const ushort4*)(nb + (cy1 * Wn + cx1) * 64 + 4 * c4);
        const float a0 = w00*bf2f(r00.x) + w01*bf2f(r01.x) + w10*bf2f(r10.x) + w11*bf2f(r11.x);
        const float a1 = w00*bf2f(r00.y) + w01*bf2f(r01.y) + w10*bf2f(r10.y) + w11*bf2f(r11.y);
        const float a2 = w00*bf2f(r00.z) + w01*bf2f(r01.z) + w10*bf2f(r10.z) + w11*bf2f(r11.z);
        const float a3 = w00*bf2f(r00.w) + w01*bf2f(r01.w) + w10*bf2f(r10.w) + w11*bf2f(r11.w);
        ushort4 pk;
        pk.x = f2bf(a0); pk.y = f2bf(a1); pk.z = f2bf(a2); pk.w = f2bf(a3);
        *(ushort4*)(cp + k * 64) = pk;
    }
}

// ---------------- gemm: barrier-free, LDS-free MFMA over cols ----------------
__global__ __launch_bounds__(256)
__attribute__((amdgpu_waves_per_eu(4, 4)))
void dcnv2_gemm(
    const ushort* __restrict__ wb,     // [64][576] bf16, ck = k*64+c
    const ushort* __restrict__ cols,   // [B*HW][576] bf16
    const float*  __restrict__ bias,
    float* __restrict__ out)
{
    const int t    = threadIdx.x;
    const int lane = t & 63;
    const int wv   = t >> 6;                       // o-strip
    const int g    = blockIdx.x;
    const int gblk = (g & 7) * 144 + (g >> 3);     // XCD-bijective (1152 = 8*144)
    const int o_m  = lane & 15;
    const int kq   = lane >> 4;

    // A-fragments: 16 o-rows x 576 ck, pinned for both pixel half-tiles
    f32x4 afr[18];
    {
        const ushort* wrow = wb + (size_t)(wv * 16 + o_m) * CK + kq * 8;
        #pragma unroll
        for (int s = 0; s < 18; ++s)
            afr[s] = *(const f32x4*)(wrow + s * 32);
    }

    const int orow = wv * 16 + (lane >> 4) * 4;
    float bi[4];
    #pragma unroll
    for (int r = 0; r < 4; ++r) bi[r] = bias[orow + r];

    #pragma unroll
    for (int half = 0; half < 2; ++half) {
        const int P0 = gblk * 32 + half * PIX;     // global pixel base
        const ushort* crow = cols + ((size_t)P0 + (lane & 15)) * CK + kq * 8;
        f32x4 acc = {0.f, 0.f, 0.f, 0.f};
        #pragma unroll 6
        for (int s = 0; s < 18; ++s) {
            const bf16x8 bfr = *(const bf16x8*)(crow + s * 32);
            acc = __builtin_amdgcn_mfma_f32_16x16x32_bf16(
                __builtin_bit_cast(bf16x8, afr[s]), bfr, acc, 0, 0, 0);
        }
        const int b   = P0 / HW;
        const int pix = P0 - b * HW;
        #pragma unroll
        for (int r = 0; r < 4; ++r) {
            out[((size_t)(b * Con + orow + r)) * HW + pix + (lane & 15)] = acc[r] + bi[r];
        }
    }
}

// ---------------- fallback (round-1 fp32 fused, used only if ws too small) ----------------
__global__ __launch_bounds__(256) void dcnv2_fused(
    const float* __restrict__ input, const float* __restrict__ offset,
    const float* __restrict__ mask, const float* __restrict__ weight,
    const float* __restrict__ bias, float* __restrict__ out)
{
    __shared__ float s_w[PIX*Kk][4];
    __shared__ int   s_a[PIX*Kk][4];
    __shared__ float s_samp[CK*PIX];
    const int t = threadIdx.x, blk = blockIdx.x;
    const int b = blk / NTILE, tile = blk % NTILE;
    const int pix0 = tile * PIX, ho = pix0 / Wn, wo0 = pix0 % Wn;
    if (t < PIX*Kk) {
        const int p = t / Kk, k = t - p*Kk, wo = wo0 + p, sp = ho*Wn + wo;
        const float dy = offset[(size_t)(b*2*Kk + 2*k)*HW + sp];
        const float dx = offset[(size_t)(b*2*Kk + 2*k + 1)*HW + sp];
        const float m  = mask[(size_t)(b*Kk + k)*HW + sp];
        const float py = dy + (float)(k/3) + (float)(ho - 1);
        const float px = dx + (float)(k%3) + (float)(wo - 1);
        const float fy = floorf(py), fx = floorf(px);
        const int iy0 = (int)fy, ix0 = (int)fx, iy1 = iy0+1, ix1 = ix0+1;
        const float wy = py - fy, wx = px - fx;
        const float vy0 = (iy0>=0 && iy0<Hn)?1.f:0.f, vy1 = (iy1>=0 && iy1<Hn)?1.f:0.f;
        const float vx0 = (ix0>=0 && ix0<Wn)?1.f:0.f, vx1 = (ix1>=0 && ix1<Wn)?1.f:0.f;
        const int cy0 = min(max(iy0,0),Hn-1), cy1 = min(max(iy1,0),Hn-1);
        const int cx0 = min(max(ix0,0),Wn-1), cx1 = min(max(ix1,0),Wn-1);
        s_w[t][0]=m*(1.f-wy)*(1.f-wx)*vy0*vx0; s_w[t][1]=m*(1.f-wy)*wx*vy0*vx1;
        s_w[t][2]=m*wy*(1.f-wx)*vy1*vx0;       s_w[t][3]=m*wy*wx*vy1*vx1;
        s_a[t][0]=cy0*Wn+cx0; s_a[t][1]=cy0*Wn+cx1; s_a[t][2]=cy1*Wn+cx0; s_a[t][3]=cy1*Wn+cx1;
    }
    __syncthreads();
    {
        const float* inb = input + (size_t)b*Cn*HW;
        #pragma unroll 4
        for (int e = t; e < CK*PIX; e += 256) {
            const int ck = e >> 4, p = e & 15, c = ck / 9, k = ck - c*9, pk = p*Kk + k;
            const float* ic = inb + (size_t)c*HW;
            s_samp[ck*PIX + p] = s_w[pk][0]*ic[s_a[pk][0]] + s_w[pk][1]*ic[s_a[pk][1]]
                               + s_w[pk][2]*ic[s_a[pk][2]] + s_w[pk][3]*ic[s_a[pk][3]];
        }
    }
    __syncthreads();
    const int o = t & 63, pg = t >> 6;
    const float4* wrow = (const float4*)(weight + (size_t)o*CK);
    float ax=0.f, ay=0.f, az=0.f, aw=0.f;
    #pragma unroll 4
    for (int q = 0; q < CK/4; ++q) {
        const float4 wv = wrow[q];
        const float4 s0 = *(const float4*)&s_samp[(4*q+0)*PIX + pg*4];
        const float4 s1 = *(const float4*)&s_samp[(4*q+1)*PIX + pg*4];
        const float4 s2 = *(const float4*)&s_samp[(4*q+2)*PIX + pg*4];
        const float4 s3 = *(const float4*)&s_samp[(4*q+3)*PIX + pg*4];
        ax += wv.x*s0.x + wv.y*s1.x + wv.z*s2.x + wv.w*s3.x;
        ay += wv.x*s0.y + wv.y*s1.y + wv.z*s2.y + wv.w*s3.y;
        az += wv.x*s0.z + wv.y*s1.z + wv.z*s2.z + wv.w*s3.z;
        aw += wv.x*s0.w + wv.y*s1.w + wv.z*s2.w + wv.w*s3.w;
    }
    const float bo = bias[o];
    float* op = out + (size_t)(b*Con + o)*HW + pix0 + pg*4;
    op[0]=ax+bo; op[1]=ay+bo; op[2]=az+bo; op[3]=aw+bo;
}

extern "C" void kernel_launch(void* const* d_in, const int* in_sizes, int n_in,
                              void* d_out, int out_size, void* d_ws, size_t ws_size,
                              hipStream_t stream) {
    const float* input  = (const float*)d_in[0];
    const float* offset = (const float*)d_in[1];
    const float* mask   = (const float*)d_in[2];
    const float* weight = (const float*)d_in[3];
    const float* bias   = (const float*)d_in[4];
    float* out = (float*)d_out;

    const size_t nhwc_bytes = (size_t)Bn * HW * 64 * 2;          // 4,718,592
    const size_t wb_bytes   = (size_t)Con * CK * 2;              // 73,728
    const size_t cols_bytes = (size_t)Bn * HW * CK * 2;          // 42,467,328
    if (ws_size >= nhwc_bytes + wb_bytes + cols_bytes) {
        ushort* nhwc = (ushort*)d_ws;
        ushort* wbuf = (ushort*)((char*)d_ws + nhwc_bytes);
        ushort* cols = (ushort*)((char*)d_ws + nhwc_bytes + wb_bytes);
        hipLaunchKernelGGL(dcnv2_prep,   dim3(720),  dim3(256), 0, stream,
                           input, weight, nhwc, wbuf);
        hipLaunchKernelGGL(dcnv2_sample, dim3(Bn * NTILE), dim3(256), 0, stream,
                           nhwc, offset, mask, cols);
        hipLaunchKernelGGL(dcnv2_gemm,   dim3(1152), dim3(256), 0, stream,
                           wbuf, cols, bias, out);
    } else {
        hipLaunchKernelGGL(dcnv2_fused, dim3(Bn * NTILE), dim3(256), 0, stream,
                           input, offset, mask, weight, bias, out);
    }
}

// Round 6
// 48.730 us; speedup vs baseline: 1.8148x; 1.8148x over previous
//
#include <hip/hip_runtime.h>

#define Bn  4
#define Cn  64
#define Hn  96
#define Wn  96
#define Con 64
#define Kk  9
#define HW  (Hn*Wn)     // 9216
#define PIX 16
#define CK  (Cn*Kk)     // 576
#define NTILE (HW/PIX)  // 576

typedef __attribute__((ext_vector_type(8))) short bf16x8;
typedef __attribute__((ext_vector_type(8))) unsigned short u16x8;
typedef __attribute__((ext_vector_type(4))) float f32x4;

static __device__ __forceinline__ float bf2f(ushort u) {
    return __uint_as_float(((unsigned int)u) << 16);
}
static __device__ __forceinline__ ushort f2bf(float f) {
    unsigned int u = __float_as_uint(f);
    u += 0x7FFFu + ((u >> 16) & 1u);   // RNE
    return (ushort)(u >> 16);
}

// bilinear-blend 8 channels of 4 corners, emit bf16x8 B-fragment chunk
static __device__ __forceinline__ bf16x8 blend8(
    float w00, float w01, float w10, float w11,
    u16x8 g00, u16x8 g01, u16x8 g10, u16x8 g11)
{
    u16x8 r;
    #pragma unroll
    for (int j = 0; j < 8; ++j) {
        const float v = w00 * bf2f(g00[j]) + w01 * bf2f(g01[j])
                      + w10 * bf2f(g10[j]) + w11 * bf2f(g11[j]);
        r[j] = f2bf(v);
    }
    return __builtin_bit_cast(bf16x8, r);
}

// ---------------- prep (merged): blocks 0..575 transpose NCHW->NHWC bf16,
//                  blocks 576..719 reorder weight f32 [o][c*9+k] -> bf16 [o][k*64+c]
__global__ __launch_bounds__(256) void dcnv2_prep(
    const float* __restrict__ in, const float* __restrict__ w,
    ushort* __restrict__ nhwc, ushort* __restrict__ wb)
{
    const int t = threadIdx.x;
    if (blockIdx.x < 576) {
        __shared__ ushort tile[64][66];
        const int bid = blockIdx.x;
        const int b  = bid / 144;
        const int s0 = (bid % 144) * 64;
        const float* ib = in + (size_t)b * Cn * HW;
        #pragma unroll
        for (int i = 0; i < 16; ++i) {
            const int c = i * 4 + (t >> 6);
            tile[t & 63][c] = f2bf(ib[(size_t)c * HW + s0 + (t & 63)]);
        }
        __syncthreads();
        ushort* ob = nhwc + ((size_t)b * HW + s0) * 64;
        #pragma unroll
        for (int i = 0; i < 16; ++i) {
            const int s = i * 4 + (t >> 6);
            ob[s * 64 + (t & 63)] = tile[s][t & 63];
        }
    } else {
        const int e = (blockIdx.x - 576) * 256 + t;
        if (e < Con * CK) {
            const int o  = e / CK;
            const int ck = e - o * CK;     // k*64 + c
            const int k  = ck >> 6;
            const int c  = ck & 63;
            wb[e] = f2bf(w[(size_t)o * CK + c * Kk + k]);
        }
    }
}

// ---------------- main: one wave per 16-px tile, no LDS, no barriers ----------------
__global__ __launch_bounds__(64)
__attribute__((amdgpu_waves_per_eu(2, 8)))
void dcnv2_wave(
    const ushort* __restrict__ nhwc,   // [B][HW][64] bf16
    const ushort* __restrict__ wb,     // [64][576] bf16, ck = k*64+c
    const float*  __restrict__ offset,
    const float*  __restrict__ mask,
    const float*  __restrict__ bias,
    float* __restrict__ out)
{
    const int lane = threadIdx.x;      // 0..63
    const int orig = blockIdx.x;
    const int tile = (orig & 7) * 288 + (orig >> 3);   // XCD-bijective (2304=8*288)
    const int b    = tile / NTILE;
    const int t16  = tile % NTILE;
    const int pix0 = t16 * PIX;
    const int ho   = pix0 / Wn;
    const int wo0  = pix0 % Wn;
    const int px   = lane & 15;
    const int q    = lane >> 4;
    const int wo   = wo0 + px;
    const int sp   = ho * Wn + wo;

    // ---- prefetch all offset/mask values (27 independent HBM loads) ----
    const float* __restrict__ ob = offset + (size_t)b * 2 * Kk * HW + sp;
    const float* __restrict__ mb = mask   + (size_t)b * Kk * HW + sp;
    float dyv[9], dxv[9], mmv[9];
    #pragma unroll
    for (int k = 0; k < 9; ++k) {
        dyv[k] = ob[(size_t)(2 * k) * HW];
        dxv[k] = ob[(size_t)(2 * k + 1) * HW];
        mmv[k] = mb[(size_t)k * HW];
    }

    const ushort* __restrict__ nb = nhwc + (size_t)b * HW * 64;
    const ushort* __restrict__ wl = wb + (size_t)px * CK + q * 8;  // + strip*16*CK + (2k+s2)*32

    f32x4 acc0 = {0.f,0.f,0.f,0.f}, acc1 = {0.f,0.f,0.f,0.f};
    f32x4 acc2 = {0.f,0.f,0.f,0.f}, acc3 = {0.f,0.f,0.f,0.f};

    #pragma unroll
    for (int k = 0; k < 9; ++k) {
        // ---- bilinear params (per-lane, redundant across q — no sharing needed) ----
        const float py = dyv[k] + (float)(k / 3) + (float)(ho - 1);
        const float pxf = dxv[k] + (float)(k % 3) + (float)(wo - 1);
        const float fy = floorf(py), fx = floorf(pxf);
        const int iy0 = (int)fy, ix0 = (int)fx;
        const int iy1 = iy0 + 1, ix1 = ix0 + 1;
        const float wy = py - fy, wx = pxf - fx;
        const float vy0 = (iy0 >= 0 && iy0 < Hn) ? 1.f : 0.f;
        const float vy1 = (iy1 >= 0 && iy1 < Hn) ? 1.f : 0.f;
        const float vx0 = (ix0 >= 0 && ix0 < Wn) ? 1.f : 0.f;
        const float vx1 = (ix1 >= 0 && ix1 < Wn) ? 1.f : 0.f;
        const int cy0 = min(max(iy0, 0), Hn - 1), cy1 = min(max(iy1, 0), Hn - 1);
        const int cx0 = min(max(ix0, 0), Wn - 1), cx1 = min(max(ix1, 0), Wn - 1);
        const float m = mmv[k];
        const float w00 = m * (1.f - wy) * (1.f - wx) * vy0 * vx0;
        const float w01 = m * (1.f - wy) * wx         * vy0 * vx1;
        const float w10 = m * wy         * (1.f - wx) * vy1 * vx0;
        const float w11 = m * wy         * wx         * vy1 * vx1;
        const int a00 = (cy0 * Wn + cx0) * 64 + q * 8;
        const int a01 = (cy0 * Wn + cx1) * 64 + q * 8;
        const int a10 = (cy1 * Wn + cx0) * 64 + q * 8;
        const int a11 = (cy1 * Wn + cx1) * 64 + q * 8;

        // ---- 8 independent gathers (two 32-ch sub-steps x 4 corners) ----
        const u16x8 g00a = *(const u16x8*)(nb + a00);
        const u16x8 g01a = *(const u16x8*)(nb + a01);
        const u16x8 g10a = *(const u16x8*)(nb + a10);
        const u16x8 g11a = *(const u16x8*)(nb + a11);
        const u16x8 g00b = *(const u16x8*)(nb + a00 + 32);
        const u16x8 g01b = *(const u16x8*)(nb + a01 + 32);
        const u16x8 g10b = *(const u16x8*)(nb + a10 + 32);
        const u16x8 g11b = *(const u16x8*)(nb + a11 + 32);

        // ---- 8 independent afrag loads (4 strips x 2 sub-steps), L2-hot ----
        const ushort* wk = wl + (2 * k) * 32;
        const bf16x8 af0a = *(const bf16x8*)(wk);
        const bf16x8 af0b = *(const bf16x8*)(wk + 32);
        const bf16x8 af1a = *(const bf16x8*)(wk + 16 * CK);
        const bf16x8 af1b = *(const bf16x8*)(wk + 16 * CK + 32);
        const bf16x8 af2a = *(const bf16x8*)(wk + 32 * CK);
        const bf16x8 af2b = *(const bf16x8*)(wk + 32 * CK + 32);
        const bf16x8 af3a = *(const bf16x8*)(wk + 48 * CK);
        const bf16x8 af3b = *(const bf16x8*)(wk + 48 * CK + 32);

        // ---- blend -> B fragments ----
        const bf16x8 bfa = blend8(w00, w01, w10, w11, g00a, g01a, g10a, g11a);
        const bf16x8 bfb = blend8(w00, w01, w10, w11, g00b, g01b, g10b, g11b);

        // ---- 8 MFMA ----
        acc0 = __builtin_amdgcn_mfma_f32_16x16x32_bf16(af0a, bfa, acc0, 0, 0, 0);
        acc0 = __builtin_amdgcn_mfma_f32_16x16x32_bf16(af0b, bfb, acc0, 0, 0, 0);
        acc1 = __builtin_amdgcn_mfma_f32_16x16x32_bf16(af1a, bfa, acc1, 0, 0, 0);
        acc1 = __builtin_amdgcn_mfma_f32_16x16x32_bf16(af1b, bfb, acc1, 0, 0, 0);
        acc2 = __builtin_amdgcn_mfma_f32_16x16x32_bf16(af2a, bfa, acc2, 0, 0, 0);
        acc2 = __builtin_amdgcn_mfma_f32_16x16x32_bf16(af2b, bfb, acc2, 0, 0, 0);
        acc3 = __builtin_amdgcn_mfma_f32_16x16x32_bf16(af3a, bfa, acc3, 0, 0, 0);
        acc3 = __builtin_amdgcn_mfma_f32_16x16x32_bf16(af3b, bfb, acc3, 0, 0, 0);
    }

    // ---- epilogue: D col = lane&15 = px, row = q*4 + r; o = strip*16 + row ----
    float* __restrict__ op = out + (size_t)b * Con * HW + pix0 + px;
    const int orow = q * 4;
    #pragma unroll
    for (int r = 0; r < 4; ++r)
        op[(size_t)(orow + r) * HW] = acc0[r] + bias[orow + r];
    #pragma unroll
    for (int r = 0; r < 4; ++r)
        op[(size_t)(16 + orow + r) * HW] = acc1[r] + bias[16 + orow + r];
    #pragma unroll
    for (int r = 0; r < 4; ++r)
        op[(size_t)(32 + orow + r) * HW] = acc2[r] + bias[32 + orow + r];
    #pragma unroll
    for (int r = 0; r < 4; ++r)
        op[(size_t)(48 + orow + r) * HW] = acc3[r] + bias[48 + orow + r];
}

// ---------------- fallback (round-1 fp32 fused, used only if ws too small) ----------------
__global__ __launch_bounds__(256) void dcnv2_fused(
    const float* __restrict__ input, const float* __restrict__ offset,
    const float* __restrict__ mask, const float* __restrict__ weight,
    const float* __restrict__ bias, float* __restrict__ out)
{
    __shared__ float s_w[PIX*Kk][4];
    __shared__ int   s_a[PIX*Kk][4];
    __shared__ float s_samp[CK*PIX];
    const int t = threadIdx.x, blk = blockIdx.x;
    const int b = blk / NTILE, tile = blk % NTILE;
    const int pix0 = tile * PIX, ho = pix0 / Wn, wo0 = pix0 % Wn;
    if (t < PIX*Kk) {
        const int p = t / Kk, k = t - p*Kk, wo = wo0 + p, sp = ho*Wn + wo;
        const float dy = offset[(size_t)(b*2*Kk + 2*k)*HW + sp];
        const float dx = offset[(size_t)(b*2*Kk + 2*k + 1)*HW + sp];
        const float m  = mask[(size_t)(b*Kk + k)*HW + sp];
        const float py = dy + (float)(k/3) + (float)(ho - 1);
        const float px = dx + (float)(k%3) + (float)(wo - 1);
        const float fy = floorf(py), fx = floorf(px);
        const int iy0 = (int)fy, ix0 = (int)fx, iy1 = iy0+1, ix1 = ix0+1;
        const float wy = py - fy, wx = px - fx;
        const float vy0 = (iy0>=0 && iy0<Hn)?1.f:0.f, vy1 = (iy1>=0 && iy1<Hn)?1.f:0.f;
        const float vx0 = (ix0>=0 && ix0<Wn)?1.f:0.f, vx1 = (ix1>=0 && ix1<Wn)?1.f:0.f;
        const int cy0 = min(max(iy0,0),Hn-1), cy1 = min(max(iy1,0),Hn-1);
        const int cx0 = min(max(ix0,0),Wn-1), cx1 = min(max(ix1,0),Wn-1);
        s_w[t][0]=m*(1.f-wy)*(1.f-wx)*vy0*vx0; s_w[t][1]=m*(1.f-wy)*wx*vy0*vx1;
        s_w[t][2]=m*wy*(1.f-wx)*vy1*vx0;       s_w[t][3]=m*wy*wx*vy1*vx1;
        s_a[t][0]=cy0*Wn+cx0; s_a[t][1]=cy0*Wn+cx1; s_a[t][2]=cy1*Wn+cx0; s_a[t][3]=cy1*Wn+cx1;
    }
    __syncthreads();
    {
        const float* inb = input + (size_t)b*Cn*HW;
        #pragma unroll 4
        for (int e = t; e < CK*PIX; e += 256) {
            const int ck = e >> 4, p = e & 15, c = ck / 9, k = ck - c*9, pk = p*Kk + k;
            const float* ic = inb + (size_t)c*HW;
            s_samp[ck*PIX + p] = s_w[pk][0]*ic[s_a[pk][0]] + s_w[pk][1]*ic[s_a[pk][1]]
                               + s_w[pk][2]*ic[s_a[pk][2]] + s_w[pk][3]*ic[s_a[pk][3]];
        }
    }
    __syncthreads();
    const int o = t & 63, pg = t >> 6;
    const float4* wrow = (const float4*)(weight + (size_t)o*CK);
    float ax=0.f, ay=0.f, az=0.f, aw=0.f;
    #pragma unroll 4
    for (int q = 0; q < CK/4; ++q) {
        const float4 wv = wrow[q];
        const float4 s0 = *(const float4*)&s_samp[(4*q+0)*PIX + pg*4];
        const float4 s1 = *(const float4*)&s_samp[(4*q+1)*PIX + pg*4];
        const float4 s2 = *(const float4*)&s_samp[(4*q+2)*PIX + pg*4];
        const float4 s3 = *(const float4*)&s_samp[(4*q+3)*PIX + pg*4];
        ax += wv.x*s0.x + wv.y*s1.x + wv.z*s2.x + wv.w*s3.x;
        ay += wv.x*s0.y + wv.y*s1.y + wv.z*s2.y + wv.w*s3.y;
        az += wv.x*s0.z + wv.y*s1.z + wv.z*s2.z + wv.w*s3.z;
        aw += wv.x*s0.w + wv.y*s1.w + wv.z*s2.w + wv.w*s3.w;
    }
    const float bo = bias[o];
    float* op = out + (size_t)(b*Con + o)*HW + pix0 + pg*4;
    op[0]=ax+bo; op[1]=ay+bo; op[2]=az+bo; op[3]=aw+bo;
}

extern "C" void kernel_launch(void* const* d_in, const int* in_sizes, int n_in,
                              void* d_out, int out_size, void* d_ws, size_t ws_size,
                              hipStream_t stream) {
    const float* input  = (const float*)d_in[0];
    const float* offset = (const float*)d_in[1];
    const float* mask   = (const float*)d_in[2];
    const float* weight = (const float*)d_in[3];
    const float* bias   = (const float*)d_in[4];
    float* out = (float*)d_out;

    const size_t nhwc_bytes = (size_t)Bn * HW * 64 * 2;          // 4,718,592
    const size_t wb_bytes   = (size_t)Con * CK * 2;              // 73,728
    if (ws_size >= nhwc_bytes + wb_bytes) {
        ushort* nhwc = (ushort*)d_ws;
        ushort* wbuf = (ushort*)((char*)d_ws + nhwc_bytes);
        hipLaunchKernelGGL(dcnv2_prep, dim3(720), dim3(256), 0, stream,
                           input, weight, nhwc, wbuf);
        hipLaunchKernelGGL(dcnv2_wave, dim3(Bn * NTILE), dim3(64), 0, stream,
                           nhwc, wbuf, offset, mask, bias, out);
    } else {
        hipLaunchKernelGGL(dcnv2_fused, dim3(Bn * NTILE), dim3(256), 0, stream,
                           input, offset, mask, weight, bias, out);
    }
}